// Round 10
// baseline (118.173 us; speedup 1.0000x reference)
//
#include <hip/hip_runtime.h>
#include <stdint.h>

#define DEVFN __device__ __forceinline__

// ---------- strict f32 ops (no FMA contraction, matches XLA strict mode) ----------
DEVFN float mulf(float a, float b) {
#pragma clang fp contract(off)
  return a * b;
}
DEVFN float addf(float a, float b) {
#pragma clang fp contract(off)
  return a + b;
}
DEVFN float subf(float a, float b) {
#pragma clang fp contract(off)
  return a - b;
}

// ---------- threefry2x32 (JAX), partitionable counter scheme ----------
DEVFN uint32_t tf_bits32(uint32_t k0, uint32_t k1, uint32_t ctr) {
  uint32_t ks2 = k0 ^ k1 ^ 0x1BD11BDAu;
  uint32_t x0 = k0;        // 0 + ks[0]
  uint32_t x1 = ctr + k1;  // ctr + ks[1]
#define TFR(d) { x0 += x1; x1 = (x1 << (d)) | (x1 >> (32 - (d))); x1 ^= x0; }
  TFR(13) TFR(15) TFR(26) TFR(6)
  x0 += k1; x1 += ks2 + 1u;
  TFR(17) TFR(29) TFR(16) TFR(24)
  x0 += ks2; x1 += k0 + 2u;
  TFR(13) TFR(15) TFR(26) TFR(6)
  x0 += k0; x1 += k1 + 3u;
  TFR(17) TFR(29) TFR(16) TFR(24)
  x0 += k1; x1 += ks2 + 4u;
  TFR(13) TFR(15) TFR(26) TFR(6)
  x0 += ks2; x1 += k0 + 5u;
#undef TFR
  return x0 ^ x1;
}

// ---------- XLA-CPU Cephes log, unfused ----------
DEVFN float xla_cephes_logf(float in) {
  float xv = fmaxf(in, __uint_as_float(0x00800000u));
  uint32_t bits = __float_as_uint(xv);
  int ei = (int)(bits >> 23) - 126;
  float m = __uint_as_float((bits & 0x007FFFFFu) | 0x3F000000u);
  float e = (float)ei;
  const float SQRTHF = __uint_as_float(0x3F3504F3u);
  bool lt = m < SQRTHF;
  float tmp = lt ? m : 0.0f;
  m = subf(m, 1.0f);
  e = subf(e, lt ? 1.0f : 0.0f);
  m = addf(m, tmp);
  float z = mulf(m, m);
  float y = 7.0376836292E-2f;
  y = addf(mulf(y, m), -1.1514610310E-1f);
  y = addf(mulf(y, m),  1.1676998740E-1f);
  y = addf(mulf(y, m), -1.2420140846E-1f);
  y = addf(mulf(y, m),  1.4249322787E-1f);
  y = addf(mulf(y, m), -1.6668057665E-1f);
  y = addf(mulf(y, m),  2.0000714765E-1f);
  y = addf(mulf(y, m), -2.4999993993E-1f);
  y = addf(mulf(y, m),  3.3333331174E-1f);
  y = mulf(y, m);
  y = mulf(y, z);
  y = addf(y, mulf(e, -2.12194440e-4f));
  y = subf(y, mulf(z, 0.5f));
  m = addf(m, y);
  m = addf(m, mulf(e, 0.693359375f));
  return m;
}

DEVFN float xla_log1pf(float a) {
  float large = xla_cephes_logf(addf(a, 1.0f));
  float small = mulf(addf(mulf(-0.5f, a), 1.0f), a);
  return (fabsf(a) < __uint_as_float(0x38D1B717u)) ? small : large;
}

DEVFN float xla_erfinvf(float u) {
  float nxx = -mulf(u, u);
  float w = -xla_log1pf(nxx);
  float p;
  if (w < 5.0f) {
    float s = subf(w, 2.5f);
    p = 2.81022636e-08f;
    p = addf(mulf(p, s), 3.43273939e-07f);
    p = addf(mulf(p, s), -3.5233877e-06f);
    p = addf(mulf(p, s), -4.39150654e-06f);
    p = addf(mulf(p, s), 0.00021858087f);
    p = addf(mulf(p, s), -0.00125372503f);
    p = addf(mulf(p, s), -0.00417768164f);
    p = addf(mulf(p, s), 0.246640727f);
    p = addf(mulf(p, s), 1.50140941f);
  } else {
    float s = subf(__fsqrt_rn(w), 3.0f);
    p = -0.000200214257f;
    p = addf(mulf(p, s), 0.000100950558f);
    p = addf(mulf(p, s), 0.00134934322f);
    p = addf(mulf(p, s), -0.00367342844f);
    p = addf(mulf(p, s), 0.00573950773f);
    p = addf(mulf(p, s), -0.0076224613f);
    p = addf(mulf(p, s), 0.00943887047f);
    p = addf(mulf(p, s), 1.00167406f);
    p = addf(mulf(p, s), 2.83297682f);
  }
  return mulf(p, u);
}

DEVFN float unitf(uint32_t bits) {
  return subf(__uint_as_float((bits >> 9) | 0x3F800000u), 1.0f);
}

DEVFN float jax_normal(uint32_t bits) {
  float f = unitf(bits);
  const float lo = __uint_as_float(0xBF7FFFFFu);
  float u = fmaxf(lo, addf(mulf(f, 2.0f), lo));
  const float sqrt2 = __uint_as_float(0x3FB504F3u);
  return mulf(sqrt2, xla_erfinvf(u));
}

struct PMKeys {
  uint32_t ki0, ki1;
  uint32_t sk[5][4][2];
};
struct NK { uint32_t k[20][2]; };

// candidate coord: clamp(addf(base, mulf(n, sigma)), 0, 255) — exact ref ops
DEVFN float candf(float base, float n, float sig) {
  return fminf(fmaxf(addf(base, mulf(n, sig)), 0.0f), 255.0f);
}
DEVFN int addr_of(float yy, float xx) {
  int iy = (int)rintf(yy);
  int ix = (int)rintf(xx);
  iy = min(max(iy, 0), 255);
  ix = min(max(ix, 0), 255);
  return iy * 256 + ix;
}

// ========================================================================
// FAST PATH
// ========================================================================

// K1: Q4[b][y][cq][x] (float4 = channels 4cq..4cq+3) = (S-T)^2 via LDS
// transpose; float4-vectorized S/T loads; inline 10 jax normals per thread
// slotted while the loads are in flight. 2048 blocks, 8.7 KB LDS.
__global__ __launch_bounds__(256) void qdiff_n(const float4* __restrict__ S4,
                                               const float4* __restrict__ T4,
                                               float4* __restrict__ Q4,
                                               float* __restrict__ N,
                                               NK nk) {
  __shared__ float lds[64 * 33];
  const int t = threadIdx.x;
  const int bid = blockIdx.x;
  const int xcd = bid & 7;
  const int slot = bid >> 3;             // 0..255
  const int r = xcd * 64 + (slot >> 2);  // 0..511 == b*256 + y
  const int q = slot & 3;
  const int b = r >> 8;
  const int y = r & 255;
  const int x0 = q << 6;                 // pixel offset of this quarter
  const int c = t >> 3;                  // channel 0..31
  const int j0 = t & 7;                  // float4 index within quarter (and +8)

  // issue 8 float4 global loads (quarter row = 16 float4 per channel)
  const size_t fbase = (size_t)(b * 32 + c) * 16384 + (size_t)y * 64 + (x0 >> 2);
  float4 s0 = S4[fbase + j0];
  float4 s1 = S4[fbase + j0 + 8];
  float4 t0 = T4[fbase + j0];
  float4 t1 = T4[fbase + j0 + 8];

  // normals while loads are in flight (pure VALU, independent)
  uint32_t gtid = (uint32_t)bid * 256u + (uint32_t)t;
#pragma unroll
  for (int i = 0; i < 10; ++i) {
    uint32_t L = (uint32_t)i * 524288u + gtid;
    uint32_t ts = L >> 18;
    uint32_t idx = L & 262143u;
    N[L] = jax_normal(tf_bits32(nk.k[ts][0], nk.k[ts][1], idx));
  }

  // consume loads -> LDS transpose (lds[px_local][c], pad 33)
  {
    float d;
    int p0 = (j0 << 2) * 33 + c;        // px_local = j0*4
    d = subf(s0.x, t0.x); lds[p0]           = mulf(d, d);
    d = subf(s0.y, t0.y); lds[p0 + 33]      = mulf(d, d);
    d = subf(s0.z, t0.z); lds[p0 + 66]      = mulf(d, d);
    d = subf(s0.w, t0.w); lds[p0 + 99]      = mulf(d, d);
    int p1 = ((j0 + 8) << 2) * 33 + c;  // px_local = (j0+8)*4
    d = subf(s1.x, t1.x); lds[p1]           = mulf(d, d);
    d = subf(s1.y, t1.y); lds[p1 + 33]      = mulf(d, d);
    d = subf(s1.z, t1.z); lds[p1 + 66]      = mulf(d, d);
    d = subf(s1.w, t1.w); lds[p1 + 99]      = mulf(d, d);
  }
  __syncthreads();
  // write cq-planar: per k, lanes cover 64 consecutive x of one cq plane
  const size_t base4 = (((size_t)b * 256 + y) * 8) * 256;
#pragma unroll
  for (int k = 0; k < 2; ++k) {
    int cq = (k << 2) + (t >> 6);  // 0..7
    int px = t & 63;
    int lb = px * 33 + cq * 4;
    float4 v;
    v.x = lds[lb];
    v.y = lds[lb + 1];
    v.z = lds[lb + 2];
    v.w = lds[lb + 3];
    Q4[base4 + (size_t)cq * 256 + x0 + px] = v;
  }
}

// K2: D[b][y][x] strict (py,px,c) linear chain from cq-planar Q4.
// ANTI-SPILL (this round): `#pragma unroll 1` on py/px so only ONE tap's
// 8 float4 (32 VGPRs) is live at a time — the previous full unroll exposed
// 72 float4 loads (288 VGPRs of results) to the scheduler, a scratch-spill
// recipe at 2 waves/SIMD. Chain order unchanged: bitwise identical.
__global__ __launch_bounds__(256) void dsum3(const float4* __restrict__ Q4,
                                             float* __restrict__ D) {
  const int x = threadIdx.x;
  const int bid = blockIdx.x;
  const int swz = (bid & 7) * 64 + (bid >> 3);  // 512 % 8 == 0: bijective
  const int y = swz & 255;
  const int b = swz >> 8;
  const float4* Qb = Q4 + (size_t)b * 524288;  // 256*8*256

  float acc = 0.0f;
#pragma unroll 1
  for (int py = 0; py < 3; ++py) {
    int yy = y + py - 1;
    if (yy < 0 || yy > 255) continue;
    const float4* Qrow = Qb + (size_t)yy * 2048;
#pragma unroll 1
    for (int px = 0; px < 3; ++px) {
      int xx = x + px - 1;
      if (xx < 0 || xx > 255) continue;
      float4 v0 = Qrow[xx];
      float4 v1 = Qrow[256 + xx];
      float4 v2 = Qrow[512 + xx];
      float4 v3 = Qrow[768 + xx];
      float4 v4 = Qrow[1024 + xx];
      float4 v5 = Qrow[1280 + xx];
      float4 v6 = Qrow[1536 + xx];
      float4 v7 = Qrow[1792 + xx];
      acc = addf(acc, v0.x); acc = addf(acc, v0.y); acc = addf(acc, v0.z); acc = addf(acc, v0.w);
      acc = addf(acc, v1.x); acc = addf(acc, v1.y); acc = addf(acc, v1.z); acc = addf(acc, v1.w);
      acc = addf(acc, v2.x); acc = addf(acc, v2.y); acc = addf(acc, v2.z); acc = addf(acc, v2.w);
      acc = addf(acc, v3.x); acc = addf(acc, v3.y); acc = addf(acc, v3.z); acc = addf(acc, v3.w);
      acc = addf(acc, v4.x); acc = addf(acc, v4.y); acc = addf(acc, v4.z); acc = addf(acc, v4.w);
      acc = addf(acc, v5.x); acc = addf(acc, v5.y); acc = addf(acc, v5.z); acc = addf(acc, v5.w);
      acc = addf(acc, v6.x); acc = addf(acc, v6.y); acc = addf(acc, v6.z); acc = addf(acc, v6.w);
      acc = addf(acc, v7.x); acc = addf(acc, v7.y); acc = addf(acc, v7.z); acc = addf(acc, v7.w);
    }
  }
  D[(b * 256 + y) * 256 + x] = acc;
}

// K3: PatchMatch loop. Random search uses a speculative acceptance tree:
// all 15 candidate positions (1+2+4+8 over accept histories) are pure
// functions of the post-propagate state -> issue all 15 loads at once,
// resolve with nested selects. Bitwise identical to the sequential chain.
__global__ __launch_bounds__(256) void pm_fast(const float* __restrict__ D,
                                               const float* __restrict__ N,
                                               float* __restrict__ out,
                                               uint32_t ki0, uint32_t ki1) {
  const int j = threadIdx.x;
  const int bb = blockIdx.x >> 8;
  const int i = blockIdx.x & 255;
  const float* Db = D + bb * 65536;
  __shared__ float sy[256], sx[256];

  const uint32_t idx_y = (uint32_t)(bb * 131072 + i * 256 + j);
  const uint32_t idx_x = idx_y + 65536u;

  float nyv[20], nxv[20];
#pragma unroll
  for (int ts = 0; ts < 20; ++ts) {
    nyv[ts] = N[(size_t)ts * 262144 + idx_y];
    nxv[ts] = N[(size_t)ts * 262144 + idx_x];
  }

  float y = mulf(unitf(tf_bits32(ki0, ki1, idx_y)), 255.0f);
  float x = mulf(unitf(tf_bits32(ki0, ki1, idx_x)), 255.0f);

  float curd = Db[addr_of(y, x)];
#pragma unroll
  for (int t = 0; t < 5; ++t) {
    // propagate +1: shifted[j] = nnf[j-1]
    sy[j] = y; sx[j] = x;
    __syncthreads();
    {
      int jn = (j + 255) & 255;
      float yn = sy[jn], xn = sx[jn];
      float shf = Db[addr_of(yn, xn)];
      if (shf < curd) { y = yn; x = xn; curd = shf; }
    }
    __syncthreads();
    // propagate -1: shifted[j] = nnf[j+1]
    sy[j] = y; sx[j] = x;
    __syncthreads();
    {
      int jn = (j + 1) & 255;
      float yn = sy[jn], xn = sx[jn];
      float shf = Db[addr_of(yn, xn)];
      if (shf < curd) { y = yn; x = xn; curd = shf; }
    }
    __syncthreads();

    // ---- speculative-tree random search ----
    float n0y = nyv[t * 4 + 0], n0x = nxv[t * 4 + 0];
    float n1y = nyv[t * 4 + 1], n1x = nxv[t * 4 + 1];
    float n2y = nyv[t * 4 + 2], n2x = nxv[t * 4 + 2];
    float n3y = nyv[t * 4 + 3], n3x = nxv[t * 4 + 3];

    float c0y = candf(y, n0y, 1.0f),  c0x = candf(x, n0x, 1.0f);
    float c1Ay = candf(y,   n1y, 0.5f), c1Ax = candf(x,   n1x, 0.5f);
    float c1By = candf(c0y, n1y, 0.5f), c1Bx = candf(c0x, n1x, 0.5f);
    float c2_0y = candf(y,    n2y, 0.25f), c2_0x = candf(x,    n2x, 0.25f);
    float c2_1y = candf(c1Ay, n2y, 0.25f), c2_1x = candf(c1Ax, n2x, 0.25f);
    float c2_2y = candf(c0y,  n2y, 0.25f), c2_2x = candf(c0x,  n2x, 0.25f);
    float c2_3y = candf(c1By, n2y, 0.25f), c2_3x = candf(c1Bx, n2x, 0.25f);
    float c3_0y = candf(y,     n3y, 0.125f), c3_0x = candf(x,     n3x, 0.125f);
    float c3_1y = candf(c2_0y, n3y, 0.125f), c3_1x = candf(c2_0x, n3x, 0.125f);
    float c3_2y = candf(c1Ay,  n3y, 0.125f), c3_2x = candf(c1Ax,  n3x, 0.125f);
    float c3_3y = candf(c2_1y, n3y, 0.125f), c3_3x = candf(c2_1x, n3x, 0.125f);
    float c3_4y = candf(c0y,   n3y, 0.125f), c3_4x = candf(c0x,   n3x, 0.125f);
    float c3_5y = candf(c2_2y, n3y, 0.125f), c3_5x = candf(c2_2x, n3x, 0.125f);
    float c3_6y = candf(c1By,  n3y, 0.125f), c3_6x = candf(c1Bx,  n3x, 0.125f);
    float c3_7y = candf(c2_3y, n3y, 0.125f), c3_7x = candf(c2_3x, n3x, 0.125f);

    float d0   = Db[addr_of(c0y,  c0x)];
    float d1A  = Db[addr_of(c1Ay, c1Ax)];
    float d1B  = Db[addr_of(c1By, c1Bx)];
    float d2_0 = Db[addr_of(c2_0y, c2_0x)];
    float d2_1 = Db[addr_of(c2_1y, c2_1x)];
    float d2_2 = Db[addr_of(c2_2y, c2_2x)];
    float d2_3 = Db[addr_of(c2_3y, c2_3x)];
    float d3_0 = Db[addr_of(c3_0y, c3_0x)];
    float d3_1 = Db[addr_of(c3_1y, c3_1x)];
    float d3_2 = Db[addr_of(c3_2y, c3_2x)];
    float d3_3 = Db[addr_of(c3_3y, c3_3x)];
    float d3_4 = Db[addr_of(c3_4y, c3_4x)];
    float d3_5 = Db[addr_of(c3_5y, c3_5x)];
    float d3_6 = Db[addr_of(c3_6y, c3_6x)];
    float d3_7 = Db[addr_of(c3_7y, c3_7x)];

    bool a0 = d0 < curd;
    y = a0 ? c0y : y;  x = a0 ? c0x : x;  curd = a0 ? d0 : curd;

    float s1y = a0 ? c1By : c1Ay, s1x = a0 ? c1Bx : c1Ax, s1d = a0 ? d1B : d1A;
    bool a1 = s1d < curd;
    y = a1 ? s1y : y;  x = a1 ? s1x : x;  curd = a1 ? s1d : curd;

    float s2y = a0 ? (a1 ? c2_3y : c2_2y) : (a1 ? c2_1y : c2_0y);
    float s2x = a0 ? (a1 ? c2_3x : c2_2x) : (a1 ? c2_1x : c2_0x);
    float s2d = a0 ? (a1 ? d2_3 : d2_2) : (a1 ? d2_1 : d2_0);
    bool a2 = s2d < curd;
    y = a2 ? s2y : y;  x = a2 ? s2x : x;  curd = a2 ? s2d : curd;

    float s3y = a0 ? (a1 ? (a2 ? c3_7y : c3_6y) : (a2 ? c3_5y : c3_4y))
                   : (a1 ? (a2 ? c3_3y : c3_2y) : (a2 ? c3_1y : c3_0y));
    float s3x = a0 ? (a1 ? (a2 ? c3_7x : c3_6x) : (a2 ? c3_5x : c3_4x))
                   : (a1 ? (a2 ? c3_3x : c3_2x) : (a2 ? c3_1x : c3_0x));
    float s3d = a0 ? (a1 ? (a2 ? d3_7 : d3_6) : (a2 ? d3_5 : d3_4))
                   : (a1 ? (a2 ? d3_3 : d3_2) : (a2 ? d3_1 : d3_0));
    bool a3 = s3d < curd;
    y = a3 ? s3y : y;  x = a3 ? s3x : x;  curd = a3 ? s3d : curd;
  }
  out[idx_y] = y;
  out[idx_x] = x;
}

// ========================================================================
// FALLBACK PATH (round-1, proven) — used if ws_size too small
// ========================================================================

__global__ __launch_bounds__(256) void compute_d(const float* __restrict__ S,
                                                 const float* __restrict__ T,
                                                 float* __restrict__ D) {
  const int x = threadIdx.x;
  const int y = blockIdx.x & 255;
  const int b = blockIdx.x >> 8;
  const int chs = 65536;
  const float* Sb = S + (size_t)b * 32 * chs;
  const float* Tb = T + (size_t)b * 32 * chs;
  float acc = 0.0f;
  for (int py = 0; py < 3; ++py) {
    int yy = y + py - 1;
    if (yy < 0 || yy > 255) continue;
    for (int px = 0; px < 3; ++px) {
      int xx = x + px - 1;
      if (xx < 0 || xx > 255) continue;
      int off = yy * 256 + xx;
      for (int c = 0; c < 32; ++c) {
        float d = subf(Sb[c * chs + off], Tb[c * chs + off]);
        acc = addf(acc, mulf(d, d));
      }
    }
  }
  D[b * chs + y * 256 + x] = acc;
}

__global__ __launch_bounds__(256) void pm_kernel(const float* __restrict__ D,
                                                 float* __restrict__ out,
                                                 PMKeys K) {
  const int j = threadIdx.x;
  const int bb = blockIdx.x >> 8;
  const int i = blockIdx.x & 255;
  const float* Db = D + bb * 65536;
  __shared__ float sy[256], sx[256];

  const uint32_t idx_y = (uint32_t)(bb * 131072 + i * 256 + j);
  const uint32_t idx_x = idx_y + 65536u;

  float y = mulf(unitf(tf_bits32(K.ki0, K.ki1, idx_y)), 255.0f);
  float x = mulf(unitf(tf_bits32(K.ki0, K.ki1, idx_x)), 255.0f);

  auto lookup = [&](float yy, float xx) -> float {
    int iy = (int)rintf(yy);
    int ix = (int)rintf(xx);
    iy = min(max(iy, 0), 255);
    ix = min(max(ix, 0), 255);
    return Db[iy * 256 + ix];
  };

  for (int t = 0; t < 5; ++t) {
    sy[j] = y; sx[j] = x;
    __syncthreads();
    {
      int jn = (j + 255) & 255;
      float yn = sy[jn], xn = sx[jn];
      float cur = lookup(y, x);
      float shf = lookup(yn, xn);
      if (shf < cur) { y = yn; x = xn; }
    }
    __syncthreads();
    sy[j] = y; sx[j] = x;
    __syncthreads();
    {
      int jn = (j + 1) & 255;
      float yn = sy[jn], xn = sx[jn];
      float cur = lookup(y, x);
      float shf = lookup(yn, xn);
      if (shf < cur) { y = yn; x = xn; }
    }
    __syncthreads();
    float cur = lookup(y, x);
    float sigma = 1.0f;
    for (int s = 0; s < 4; ++s) {
      uint32_t kk0 = K.sk[t][s][0], kk1 = K.sk[t][s][1];
      float ny = jax_normal(tf_bits32(kk0, kk1, idx_y));
      float nx = jax_normal(tf_bits32(kk0, kk1, idx_x));
      float ry = fminf(fmaxf(addf(y, mulf(ny, sigma)), 0.0f), 255.0f);
      float rx = fminf(fmaxf(addf(x, mulf(nx, sigma)), 0.0f), 255.0f);
      float rd = lookup(ry, rx);
      if (rd < cur) { y = ry; x = rx; cur = rd; }
      sigma *= 0.5f;
    }
  }
  out[idx_y] = y;
  out[idx_x] = x;
}

// ---------- host-side threefry ----------
static void h_tf(uint32_t k0, uint32_t k1, uint32_t x0, uint32_t x1,
                 uint32_t& o0, uint32_t& o1) {
  uint32_t ks2 = k0 ^ k1 ^ 0x1BD11BDAu;
  x0 += k0; x1 += k1;
#define HR(d) { x0 += x1; x1 = (x1 << (d)) | (x1 >> (32 - (d))); x1 ^= x0; }
  HR(13) HR(15) HR(26) HR(6)
  x0 += k1; x1 += ks2 + 1u;
  HR(17) HR(29) HR(16) HR(24)
  x0 += ks2; x1 += k0 + 2u;
  HR(13) HR(15) HR(26) HR(6)
  x0 += k0; x1 += k1 + 3u;
  HR(17) HR(29) HR(16) HR(24)
  x0 += k1; x1 += ks2 + 4u;
  HR(13) HR(15) HR(26) HR(6)
  x0 += ks2; x1 += k0 + 5u;
#undef HR
  o0 = x0; o1 = x1;
}

extern "C" void kernel_launch(void* const* d_in, const int* in_sizes, int n_in,
                              void* d_out, int out_size, void* d_ws, size_t ws_size,
                              hipStream_t stream) {
  const float* S = (const float*)d_in[0];
  const float* T = (const float*)d_in[1];
  float* out = (float*)d_out;

  PMKeys K;
  uint32_t kl0, kl1;
  h_tf(0u, 1u, 0u, 0u, K.ki0, K.ki1);
  h_tf(0u, 1u, 0u, 1u, kl0, kl1);
  for (uint32_t t = 0; t < 5; ++t) {
    uint32_t c0, c1;
    h_tf(kl0, kl1, 0u, t, c0, c1);
    for (int s = 0; s < 4; ++s) {
      uint32_t n0, n1, s0, s1;
      h_tf(c0, c1, 0u, 0u, n0, n1);
      h_tf(c0, c1, 0u, 1u, s0, s1);
      K.sk[t][s][0] = s0; K.sk[t][s][1] = s1;
      c0 = n0; c1 = n1;
    }
  }

  const size_t D_BYTES = 2ull * 65536 * 4;       // 512 KB
  const size_t Q_BYTES = 2ull * 65536 * 32 * 4;  // 16.8 MB (cq-planar)
  const size_t N_BYTES = 20ull * 262144 * 4;     // 20 MB
  const size_t NEED = D_BYTES + Q_BYTES + N_BYTES;

  if (ws_size >= NEED) {
    float* Dd = (float*)d_ws;
    float4* Qq = (float4*)((char*)d_ws + D_BYTES);
    float* Nn = (float*)((char*)d_ws + D_BYTES + Q_BYTES);
    NK nk;
    for (int t = 0; t < 5; ++t)
      for (int s = 0; s < 4; ++s) {
        nk.k[t * 4 + s][0] = K.sk[t][s][0];
        nk.k[t * 4 + s][1] = K.sk[t][s][1];
      }
    hipLaunchKernelGGL(qdiff_n, dim3(2048), dim3(256), 0, stream,
                       (const float4*)S, (const float4*)T, Qq, Nn, nk);
    hipLaunchKernelGGL(dsum3, dim3(512), dim3(256), 0, stream, Qq, Dd);
    hipLaunchKernelGGL(pm_fast, dim3(512), dim3(256), 0, stream, Dd, Nn, out, K.ki0, K.ki1);
  } else {
    float* Dd = (float*)d_ws;
    hipLaunchKernelGGL(compute_d, dim3(512), dim3(256), 0, stream, S, T, Dd);
    hipLaunchKernelGGL(pm_kernel, dim3(512), dim3(256), 0, stream, Dd, out, K);
  }
}

// Round 11
// 118.100 us; speedup vs baseline: 1.0006x; 1.0006x over previous
//
#include <hip/hip_runtime.h>
#include <hip/hip_cooperative_groups.h>
#include <stdint.h>

#define DEVFN __device__ __forceinline__

// ---------- strict f32 ops (no FMA contraction, matches XLA strict mode) ----------
DEVFN float mulf(float a, float b) {
#pragma clang fp contract(off)
  return a * b;
}
DEVFN float addf(float a, float b) {
#pragma clang fp contract(off)
  return a + b;
}
DEVFN float subf(float a, float b) {
#pragma clang fp contract(off)
  return a - b;
}

// ---------- threefry2x32 (JAX), partitionable counter scheme ----------
DEVFN uint32_t tf_bits32(uint32_t k0, uint32_t k1, uint32_t ctr) {
  uint32_t ks2 = k0 ^ k1 ^ 0x1BD11BDAu;
  uint32_t x0 = k0;
  uint32_t x1 = ctr + k1;
#define TFR(d) { x0 += x1; x1 = (x1 << (d)) | (x1 >> (32 - (d))); x1 ^= x0; }
  TFR(13) TFR(15) TFR(26) TFR(6)
  x0 += k1; x1 += ks2 + 1u;
  TFR(17) TFR(29) TFR(16) TFR(24)
  x0 += ks2; x1 += k0 + 2u;
  TFR(13) TFR(15) TFR(26) TFR(6)
  x0 += k0; x1 += k1 + 3u;
  TFR(17) TFR(29) TFR(16) TFR(24)
  x0 += k1; x1 += ks2 + 4u;
  TFR(13) TFR(15) TFR(26) TFR(6)
  x0 += ks2; x1 += k0 + 5u;
#undef TFR
  return x0 ^ x1;
}

// ---------- XLA-CPU Cephes log, unfused ----------
DEVFN float xla_cephes_logf(float in) {
  float xv = fmaxf(in, __uint_as_float(0x00800000u));
  uint32_t bits = __float_as_uint(xv);
  int ei = (int)(bits >> 23) - 126;
  float m = __uint_as_float((bits & 0x007FFFFFu) | 0x3F000000u);
  float e = (float)ei;
  const float SQRTHF = __uint_as_float(0x3F3504F3u);
  bool lt = m < SQRTHF;
  float tmp = lt ? m : 0.0f;
  m = subf(m, 1.0f);
  e = subf(e, lt ? 1.0f : 0.0f);
  m = addf(m, tmp);
  float z = mulf(m, m);
  float y = 7.0376836292E-2f;
  y = addf(mulf(y, m), -1.1514610310E-1f);
  y = addf(mulf(y, m),  1.1676998740E-1f);
  y = addf(mulf(y, m), -1.2420140846E-1f);
  y = addf(mulf(y, m),  1.4249322787E-1f);
  y = addf(mulf(y, m), -1.6668057665E-1f);
  y = addf(mulf(y, m),  2.0000714765E-1f);
  y = addf(mulf(y, m), -2.4999993993E-1f);
  y = addf(mulf(y, m),  3.3333331174E-1f);
  y = mulf(y, m);
  y = mulf(y, z);
  y = addf(y, mulf(e, -2.12194440e-4f));
  y = subf(y, mulf(z, 0.5f));
  m = addf(m, y);
  m = addf(m, mulf(e, 0.693359375f));
  return m;
}

DEVFN float xla_log1pf(float a) {
  float large = xla_cephes_logf(addf(a, 1.0f));
  float small = mulf(addf(mulf(-0.5f, a), 1.0f), a);
  return (fabsf(a) < __uint_as_float(0x38D1B717u)) ? small : large;
}

DEVFN float xla_erfinvf(float u) {
  float nxx = -mulf(u, u);
  float w = -xla_log1pf(nxx);
  float p;
  if (w < 5.0f) {
    float s = subf(w, 2.5f);
    p = 2.81022636e-08f;
    p = addf(mulf(p, s), 3.43273939e-07f);
    p = addf(mulf(p, s), -3.5233877e-06f);
    p = addf(mulf(p, s), -4.39150654e-06f);
    p = addf(mulf(p, s), 0.00021858087f);
    p = addf(mulf(p, s), -0.00125372503f);
    p = addf(mulf(p, s), -0.00417768164f);
    p = addf(mulf(p, s), 0.246640727f);
    p = addf(mulf(p, s), 1.50140941f);
  } else {
    float s = subf(__fsqrt_rn(w), 3.0f);
    p = -0.000200214257f;
    p = addf(mulf(p, s), 0.000100950558f);
    p = addf(mulf(p, s), 0.00134934322f);
    p = addf(mulf(p, s), -0.00367342844f);
    p = addf(mulf(p, s), 0.00573950773f);
    p = addf(mulf(p, s), -0.0076224613f);
    p = addf(mulf(p, s), 0.00943887047f);
    p = addf(mulf(p, s), 1.00167406f);
    p = addf(mulf(p, s), 2.83297682f);
  }
  return mulf(p, u);
}

DEVFN float unitf(uint32_t bits) {
  return subf(__uint_as_float((bits >> 9) | 0x3F800000u), 1.0f);
}

DEVFN float jax_normal(uint32_t bits) {
  float f = unitf(bits);
  const float lo = __uint_as_float(0xBF7FFFFFu);
  float u = fmaxf(lo, addf(mulf(f, 2.0f), lo));
  const float sqrt2 = __uint_as_float(0x3FB504F3u);
  return mulf(sqrt2, xla_erfinvf(u));
}

struct PMKeys {
  uint32_t ki0, ki1;
  uint32_t sk[5][4][2];
};
struct NK { uint32_t k[20][2]; };

DEVFN float candf(float base, float n, float sig) {
  return fminf(fmaxf(addf(base, mulf(n, sig)), 0.0f), 255.0f);
}
DEVFN int addr_of(float yy, float xx) {
  int iy = (int)rintf(yy);
  int ix = (int)rintf(xx);
  iy = min(max(iy, 0), 255);
  ix = min(max(ix, 0), 255);
  return iy * 256 + ix;
}

// ========================================================================
// MEGA-KERNEL (cooperative): phase A qdiff+normals, B dsum, C patchmatch.
// 1024 blocks x 256; launch_bounds(256,4) caps VGPR at 128 (4 blocks/CU
// co-resident = 1024 blocks chip-wide, required for grid.sync).
// ========================================================================
__global__ __launch_bounds__(256, 4) void mega(const float4* __restrict__ S4,
                                               const float4* __restrict__ T4,
                                               float4* __restrict__ Q4,
                                               float* __restrict__ N,
                                               float* __restrict__ D,
                                               float* __restrict__ out,
                                               NK nk, uint32_t ki0, uint32_t ki1) {
  cooperative_groups::grid_group grid = cooperative_groups::this_grid();
  __shared__ float lds[64 * 33];
  const int tid = threadIdx.x;
  const int bid = blockIdx.x;

  // ---------------- Phase A: Q4 (2 quarter-tiles/block) + 20 normals ----------------
  const uint32_t gtid = (uint32_t)bid * 256u + (uint32_t)tid;  // 0..262143
#pragma unroll 1
  for (int k = 0; k < 2; ++k) {
    const int g = bid * 2 + k;           // quarter-tile id 0..2047
    const int b = g >> 10;
    const int y = (g >> 2) & 255;
    const int x0 = (g & 3) << 6;
    const int c = tid >> 3;
    const int j0 = tid & 7;
    const size_t fbase = (size_t)(b * 32 + c) * 16384 + (size_t)y * 64 + (x0 >> 2);
    float4 s0 = S4[fbase + j0];
    float4 s1 = S4[fbase + j0 + 8];
    float4 t0 = T4[fbase + j0];
    float4 t1 = T4[fbase + j0 + 8];

    // normals while loads are in flight
#pragma unroll
    for (int i = 0; i < 10; ++i) {
      int ts = k * 10 + i;
      N[(size_t)ts * 262144 + gtid] = jax_normal(tf_bits32(nk.k[ts][0], nk.k[ts][1], gtid));
    }

    {
      float d;
      int p0 = (j0 << 2) * 33 + c;
      d = subf(s0.x, t0.x); lds[p0]      = mulf(d, d);
      d = subf(s0.y, t0.y); lds[p0 + 33] = mulf(d, d);
      d = subf(s0.z, t0.z); lds[p0 + 66] = mulf(d, d);
      d = subf(s0.w, t0.w); lds[p0 + 99] = mulf(d, d);
      int p1 = ((j0 + 8) << 2) * 33 + c;
      d = subf(s1.x, t1.x); lds[p1]      = mulf(d, d);
      d = subf(s1.y, t1.y); lds[p1 + 33] = mulf(d, d);
      d = subf(s1.z, t1.z); lds[p1 + 66] = mulf(d, d);
      d = subf(s1.w, t1.w); lds[p1 + 99] = mulf(d, d);
    }
    __syncthreads();
    const size_t base4 = (((size_t)b * 256 + y) * 8) * 256;
#pragma unroll
    for (int kk = 0; kk < 2; ++kk) {
      int cq = (kk << 2) + (tid >> 6);
      int px = tid & 63;
      int lb = px * 33 + cq * 4;
      float4 v;
      v.x = lds[lb]; v.y = lds[lb + 1]; v.z = lds[lb + 2]; v.w = lds[lb + 3];
      Q4[base4 + (size_t)cq * 256 + x0 + px] = v;
    }
    __syncthreads();
  }

  grid.sync();

  // ---------------- Phase B: D for 128 pixels/block, strict (py,px,c) chain ----------------
  if (tid < 128) {
    const int P = bid * 128 + tid;  // 0..131071 == ((b*256+y)*256+x)
    const int b = P >> 16;
    const int rem = P & 65535;
    const int y = rem >> 8;
    const int x = rem & 255;
    const float4* Qb = Q4 + (size_t)b * 524288;
    float acc = 0.0f;
#pragma unroll 1
    for (int py = 0; py < 3; ++py) {
      int yy = y + py - 1;
      if (yy < 0 || yy > 255) continue;
      const float4* Qrow = Qb + (size_t)yy * 2048;
#pragma unroll 1
      for (int px = 0; px < 3; ++px) {
        int xx = x + px - 1;
        if (xx < 0 || xx > 255) continue;
        float4 v0 = Qrow[xx];
        float4 v1 = Qrow[256 + xx];
        float4 v2 = Qrow[512 + xx];
        float4 v3 = Qrow[768 + xx];
        float4 v4 = Qrow[1024 + xx];
        float4 v5 = Qrow[1280 + xx];
        float4 v6 = Qrow[1536 + xx];
        float4 v7 = Qrow[1792 + xx];
        acc = addf(acc, v0.x); acc = addf(acc, v0.y); acc = addf(acc, v0.z); acc = addf(acc, v0.w);
        acc = addf(acc, v1.x); acc = addf(acc, v1.y); acc = addf(acc, v1.z); acc = addf(acc, v1.w);
        acc = addf(acc, v2.x); acc = addf(acc, v2.y); acc = addf(acc, v2.z); acc = addf(acc, v2.w);
        acc = addf(acc, v3.x); acc = addf(acc, v3.y); acc = addf(acc, v3.z); acc = addf(acc, v3.w);
        acc = addf(acc, v4.x); acc = addf(acc, v4.y); acc = addf(acc, v4.z); acc = addf(acc, v4.w);
        acc = addf(acc, v5.x); acc = addf(acc, v5.y); acc = addf(acc, v5.z); acc = addf(acc, v5.w);
        acc = addf(acc, v6.x); acc = addf(acc, v6.y); acc = addf(acc, v6.z); acc = addf(acc, v6.w);
        acc = addf(acc, v7.x); acc = addf(acc, v7.y); acc = addf(acc, v7.z); acc = addf(acc, v7.w);
      }
    }
    D[P] = acc;
  }

  grid.sync();

  // ---------------- Phase C: PatchMatch (blocks 0..511) ----------------
  if (bid >= 512) return;
  float* sy = lds;        // reuse LDS (post-sync)
  float* sx = lds + 256;
  const int j = tid;
  const int bb = bid >> 8;
  const int i = bid & 255;
  const float* Db = D + bb * 65536;

  const uint32_t idx_y = (uint32_t)(bb * 131072 + i * 256 + j);
  const uint32_t idx_x = idx_y + 65536u;

  float nyv[20], nxv[20];
#pragma unroll
  for (int ts = 0; ts < 20; ++ts) {
    nyv[ts] = N[(size_t)ts * 262144 + idx_y];
    nxv[ts] = N[(size_t)ts * 262144 + idx_x];
  }

  float y = mulf(unitf(tf_bits32(ki0, ki1, idx_y)), 255.0f);
  float x = mulf(unitf(tf_bits32(ki0, ki1, idx_x)), 255.0f);

  float curd = Db[addr_of(y, x)];
#pragma unroll 1
  for (int t = 0; t < 5; ++t) {
    sy[j] = y; sx[j] = x;
    __syncthreads();
    {
      int jn = (j + 255) & 255;
      float yn = sy[jn], xn = sx[jn];
      float shf = Db[addr_of(yn, xn)];
      if (shf < curd) { y = yn; x = xn; curd = shf; }
    }
    __syncthreads();
    sy[j] = y; sx[j] = x;
    __syncthreads();
    {
      int jn = (j + 1) & 255;
      float yn = sy[jn], xn = sx[jn];
      float shf = Db[addr_of(yn, xn)];
      if (shf < curd) { y = yn; x = xn; curd = shf; }
    }
    __syncthreads();

    float n0y = nyv[t * 4 + 0], n0x = nxv[t * 4 + 0];
    float n1y = nyv[t * 4 + 1], n1x = nxv[t * 4 + 1];
    float n2y = nyv[t * 4 + 2], n2x = nxv[t * 4 + 2];
    float n3y = nyv[t * 4 + 3], n3x = nxv[t * 4 + 3];

    float c0y = candf(y, n0y, 1.0f),  c0x = candf(x, n0x, 1.0f);
    float c1Ay = candf(y,   n1y, 0.5f), c1Ax = candf(x,   n1x, 0.5f);
    float c1By = candf(c0y, n1y, 0.5f), c1Bx = candf(c0x, n1x, 0.5f);
    float c2_0y = candf(y,    n2y, 0.25f), c2_0x = candf(x,    n2x, 0.25f);
    float c2_1y = candf(c1Ay, n2y, 0.25f), c2_1x = candf(c1Ax, n2x, 0.25f);
    float c2_2y = candf(c0y,  n2y, 0.25f), c2_2x = candf(c0x,  n2x, 0.25f);
    float c2_3y = candf(c1By, n2y, 0.25f), c2_3x = candf(c1Bx, n2x, 0.25f);
    float c3_0y = candf(y,     n3y, 0.125f), c3_0x = candf(x,     n3x, 0.125f);
    float c3_1y = candf(c2_0y, n3y, 0.125f), c3_1x = candf(c2_0x, n3x, 0.125f);
    float c3_2y = candf(c1Ay,  n3y, 0.125f), c3_2x = candf(c1Ax,  n3x, 0.125f);
    float c3_3y = candf(c2_1y, n3y, 0.125f), c3_3x = candf(c2_1x, n3x, 0.125f);
    float c3_4y = candf(c0y,   n3y, 0.125f), c3_4x = candf(c0x,   n3x, 0.125f);
    float c3_5y = candf(c2_2y, n3y, 0.125f), c3_5x = candf(c2_2x, n3x, 0.125f);
    float c3_6y = candf(c1By,  n3y, 0.125f), c3_6x = candf(c1Bx,  n3x, 0.125f);
    float c3_7y = candf(c2_3y, n3y, 0.125f), c3_7x = candf(c2_3x, n3x, 0.125f);

    float d0   = Db[addr_of(c0y,  c0x)];
    float d1A  = Db[addr_of(c1Ay, c1Ax)];
    float d1B  = Db[addr_of(c1By, c1Bx)];
    float d2_0 = Db[addr_of(c2_0y, c2_0x)];
    float d2_1 = Db[addr_of(c2_1y, c2_1x)];
    float d2_2 = Db[addr_of(c2_2y, c2_2x)];
    float d2_3 = Db[addr_of(c2_3y, c2_3x)];
    float d3_0 = Db[addr_of(c3_0y, c3_0x)];
    float d3_1 = Db[addr_of(c3_1y, c3_1x)];
    float d3_2 = Db[addr_of(c3_2y, c3_2x)];
    float d3_3 = Db[addr_of(c3_3y, c3_3x)];
    float d3_4 = Db[addr_of(c3_4y, c3_4x)];
    float d3_5 = Db[addr_of(c3_5y, c3_5x)];
    float d3_6 = Db[addr_of(c3_6y, c3_6x)];
    float d3_7 = Db[addr_of(c3_7y, c3_7x)];

    bool a0 = d0 < curd;
    y = a0 ? c0y : y;  x = a0 ? c0x : x;  curd = a0 ? d0 : curd;

    float s1y = a0 ? c1By : c1Ay, s1x = a0 ? c1Bx : c1Ax, s1d = a0 ? d1B : d1A;
    bool a1 = s1d < curd;
    y = a1 ? s1y : y;  x = a1 ? s1x : x;  curd = a1 ? s1d : curd;

    float s2y = a0 ? (a1 ? c2_3y : c2_2y) : (a1 ? c2_1y : c2_0y);
    float s2x = a0 ? (a1 ? c2_3x : c2_2x) : (a1 ? c2_1x : c2_0x);
    float s2d = a0 ? (a1 ? d2_3 : d2_2) : (a1 ? d2_1 : d2_0);
    bool a2 = s2d < curd;
    y = a2 ? s2y : y;  x = a2 ? s2x : x;  curd = a2 ? s2d : curd;

    float s3y = a0 ? (a1 ? (a2 ? c3_7y : c3_6y) : (a2 ? c3_5y : c3_4y))
                   : (a1 ? (a2 ? c3_3y : c3_2y) : (a2 ? c3_1y : c3_0y));
    float s3x = a0 ? (a1 ? (a2 ? c3_7x : c3_6x) : (a2 ? c3_5x : c3_4x))
                   : (a1 ? (a2 ? c3_3x : c3_2x) : (a2 ? c3_1x : c3_0x));
    float s3d = a0 ? (a1 ? (a2 ? d3_7 : d3_6) : (a2 ? d3_5 : d3_4))
                   : (a1 ? (a2 ? d3_3 : d3_2) : (a2 ? d3_1 : d3_0));
    bool a3 = s3d < curd;
    y = a3 ? s3y : y;  x = a3 ? s3x : x;  curd = a3 ? s3d : curd;
  }
  out[idx_y] = y;
  out[idx_x] = x;
}

// ========================================================================
// Non-cooperative 3-kernel path (R9, proven) + round-1 fallback
// ========================================================================

__global__ __launch_bounds__(256) void qdiff_n(const float4* __restrict__ S4,
                                               const float4* __restrict__ T4,
                                               float4* __restrict__ Q4,
                                               float* __restrict__ N,
                                               NK nk) {
  __shared__ float lds[64 * 33];
  const int t = threadIdx.x;
  const int bid = blockIdx.x;
  const int xcd = bid & 7;
  const int slot = bid >> 3;
  const int r = xcd * 64 + (slot >> 2);
  const int q = slot & 3;
  const int b = r >> 8;
  const int y = r & 255;
  const int x0 = q << 6;
  const int c = t >> 3;
  const int j0 = t & 7;

  const size_t fbase = (size_t)(b * 32 + c) * 16384 + (size_t)y * 64 + (x0 >> 2);
  float4 s0 = S4[fbase + j0];
  float4 s1 = S4[fbase + j0 + 8];
  float4 t0 = T4[fbase + j0];
  float4 t1 = T4[fbase + j0 + 8];

  uint32_t gtid = (uint32_t)bid * 256u + (uint32_t)t;
#pragma unroll
  for (int i = 0; i < 10; ++i) {
    uint32_t L = (uint32_t)i * 524288u + gtid;
    uint32_t ts = L >> 18;
    uint32_t idx = L & 262143u;
    N[L] = jax_normal(tf_bits32(nk.k[ts][0], nk.k[ts][1], idx));
  }

  {
    float d;
    int p0 = (j0 << 2) * 33 + c;
    d = subf(s0.x, t0.x); lds[p0]      = mulf(d, d);
    d = subf(s0.y, t0.y); lds[p0 + 33] = mulf(d, d);
    d = subf(s0.z, t0.z); lds[p0 + 66] = mulf(d, d);
    d = subf(s0.w, t0.w); lds[p0 + 99] = mulf(d, d);
    int p1 = ((j0 + 8) << 2) * 33 + c;
    d = subf(s1.x, t1.x); lds[p1]      = mulf(d, d);
    d = subf(s1.y, t1.y); lds[p1 + 33] = mulf(d, d);
    d = subf(s1.z, t1.z); lds[p1 + 66] = mulf(d, d);
    d = subf(s1.w, t1.w); lds[p1 + 99] = mulf(d, d);
  }
  __syncthreads();
  const size_t base4 = (((size_t)b * 256 + y) * 8) * 256;
#pragma unroll
  for (int k = 0; k < 2; ++k) {
    int cq = (k << 2) + (t >> 6);
    int px = t & 63;
    int lb = px * 33 + cq * 4;
    float4 v;
    v.x = lds[lb]; v.y = lds[lb + 1]; v.z = lds[lb + 2]; v.w = lds[lb + 3];
    Q4[base4 + (size_t)cq * 256 + x0 + px] = v;
  }
}

__global__ __launch_bounds__(256) void dsum3(const float4* __restrict__ Q4,
                                             float* __restrict__ D) {
  const int x = threadIdx.x;
  const int bid = blockIdx.x;
  const int swz = (bid & 7) * 64 + (bid >> 3);
  const int y = swz & 255;
  const int b = swz >> 8;
  const float4* Qb = Q4 + (size_t)b * 524288;

  float acc = 0.0f;
#pragma unroll 1
  for (int py = 0; py < 3; ++py) {
    int yy = y + py - 1;
    if (yy < 0 || yy > 255) continue;
    const float4* Qrow = Qb + (size_t)yy * 2048;
#pragma unroll 1
    for (int px = 0; px < 3; ++px) {
      int xx = x + px - 1;
      if (xx < 0 || xx > 255) continue;
      float4 v0 = Qrow[xx];
      float4 v1 = Qrow[256 + xx];
      float4 v2 = Qrow[512 + xx];
      float4 v3 = Qrow[768 + xx];
      float4 v4 = Qrow[1024 + xx];
      float4 v5 = Qrow[1280 + xx];
      float4 v6 = Qrow[1536 + xx];
      float4 v7 = Qrow[1792 + xx];
      acc = addf(acc, v0.x); acc = addf(acc, v0.y); acc = addf(acc, v0.z); acc = addf(acc, v0.w);
      acc = addf(acc, v1.x); acc = addf(acc, v1.y); acc = addf(acc, v1.z); acc = addf(acc, v1.w);
      acc = addf(acc, v2.x); acc = addf(acc, v2.y); acc = addf(acc, v2.z); acc = addf(acc, v2.w);
      acc = addf(acc, v3.x); acc = addf(acc, v3.y); acc = addf(acc, v3.z); acc = addf(acc, v3.w);
      acc = addf(acc, v4.x); acc = addf(acc, v4.y); acc = addf(acc, v4.z); acc = addf(acc, v4.w);
      acc = addf(acc, v5.x); acc = addf(acc, v5.y); acc = addf(acc, v5.z); acc = addf(acc, v5.w);
      acc = addf(acc, v6.x); acc = addf(acc, v6.y); acc = addf(acc, v6.z); acc = addf(acc, v6.w);
      acc = addf(acc, v7.x); acc = addf(acc, v7.y); acc = addf(acc, v7.z); acc = addf(acc, v7.w);
    }
  }
  D[(b * 256 + y) * 256 + x] = acc;
}

__global__ __launch_bounds__(256) void pm_fast(const float* __restrict__ D,
                                               const float* __restrict__ N,
                                               float* __restrict__ out,
                                               uint32_t ki0, uint32_t ki1) {
  const int j = threadIdx.x;
  const int bb = blockIdx.x >> 8;
  const int i = blockIdx.x & 255;
  const float* Db = D + bb * 65536;
  __shared__ float sy[256], sx[256];

  const uint32_t idx_y = (uint32_t)(bb * 131072 + i * 256 + j);
  const uint32_t idx_x = idx_y + 65536u;

  float nyv[20], nxv[20];
#pragma unroll
  for (int ts = 0; ts < 20; ++ts) {
    nyv[ts] = N[(size_t)ts * 262144 + idx_y];
    nxv[ts] = N[(size_t)ts * 262144 + idx_x];
  }

  float y = mulf(unitf(tf_bits32(ki0, ki1, idx_y)), 255.0f);
  float x = mulf(unitf(tf_bits32(ki0, ki1, idx_x)), 255.0f);

  float curd = Db[addr_of(y, x)];
#pragma unroll
  for (int t = 0; t < 5; ++t) {
    sy[j] = y; sx[j] = x;
    __syncthreads();
    {
      int jn = (j + 255) & 255;
      float yn = sy[jn], xn = sx[jn];
      float shf = Db[addr_of(yn, xn)];
      if (shf < curd) { y = yn; x = xn; curd = shf; }
    }
    __syncthreads();
    sy[j] = y; sx[j] = x;
    __syncthreads();
    {
      int jn = (j + 1) & 255;
      float yn = sy[jn], xn = sx[jn];
      float shf = Db[addr_of(yn, xn)];
      if (shf < curd) { y = yn; x = xn; curd = shf; }
    }
    __syncthreads();

    float n0y = nyv[t * 4 + 0], n0x = nxv[t * 4 + 0];
    float n1y = nyv[t * 4 + 1], n1x = nxv[t * 4 + 1];
    float n2y = nyv[t * 4 + 2], n2x = nxv[t * 4 + 2];
    float n3y = nyv[t * 4 + 3], n3x = nxv[t * 4 + 3];

    float c0y = candf(y, n0y, 1.0f),  c0x = candf(x, n0x, 1.0f);
    float c1Ay = candf(y,   n1y, 0.5f), c1Ax = candf(x,   n1x, 0.5f);
    float c1By = candf(c0y, n1y, 0.5f), c1Bx = candf(c0x, n1x, 0.5f);
    float c2_0y = candf(y,    n2y, 0.25f), c2_0x = candf(x,    n2x, 0.25f);
    float c2_1y = candf(c1Ay, n2y, 0.25f), c2_1x = candf(c1Ax, n2x, 0.25f);
    float c2_2y = candf(c0y,  n2y, 0.25f), c2_2x = candf(c0x,  n2x, 0.25f);
    float c2_3y = candf(c1By, n2y, 0.25f), c2_3x = candf(c1Bx, n2x, 0.25f);
    float c3_0y = candf(y,     n3y, 0.125f), c3_0x = candf(x,     n3x, 0.125f);
    float c3_1y = candf(c2_0y, n3y, 0.125f), c3_1x = candf(c2_0x, n3x, 0.125f);
    float c3_2y = candf(c1Ay,  n3y, 0.125f), c3_2x = candf(c1Ax,  n3x, 0.125f);
    float c3_3y = candf(c2_1y, n3y, 0.125f), c3_3x = candf(c2_1x, n3x, 0.125f);
    float c3_4y = candf(c0y,   n3y, 0.125f), c3_4x = candf(c0x,   n3x, 0.125f);
    float c3_5y = candf(c2_2y, n3y, 0.125f), c3_5x = candf(c2_2x, n3x, 0.125f);
    float c3_6y = candf(c1By,  n3y, 0.125f), c3_6x = candf(c1Bx,  n3x, 0.125f);
    float c3_7y = candf(c2_3y, n3y, 0.125f), c3_7x = candf(c2_3x, n3x, 0.125f);

    float d0   = Db[addr_of(c0y,  c0x)];
    float d1A  = Db[addr_of(c1Ay, c1Ax)];
    float d1B  = Db[addr_of(c1By, c1Bx)];
    float d2_0 = Db[addr_of(c2_0y, c2_0x)];
    float d2_1 = Db[addr_of(c2_1y, c2_1x)];
    float d2_2 = Db[addr_of(c2_2y, c2_2x)];
    float d2_3 = Db[addr_of(c2_3y, c2_3x)];
    float d3_0 = Db[addr_of(c3_0y, c3_0x)];
    float d3_1 = Db[addr_of(c3_1y, c3_1x)];
    float d3_2 = Db[addr_of(c3_2y, c3_2x)];
    float d3_3 = Db[addr_of(c3_3y, c3_3x)];
    float d3_4 = Db[addr_of(c3_4y, c3_4x)];
    float d3_5 = Db[addr_of(c3_5y, c3_5x)];
    float d3_6 = Db[addr_of(c3_6y, c3_6x)];
    float d3_7 = Db[addr_of(c3_7y, c3_7x)];

    bool a0 = d0 < curd;
    y = a0 ? c0y : y;  x = a0 ? c0x : x;  curd = a0 ? d0 : curd;

    float s1y = a0 ? c1By : c1Ay, s1x = a0 ? c1Bx : c1Ax, s1d = a0 ? d1B : d1A;
    bool a1 = s1d < curd;
    y = a1 ? s1y : y;  x = a1 ? s1x : x;  curd = a1 ? s1d : curd;

    float s2y = a0 ? (a1 ? c2_3y : c2_2y) : (a1 ? c2_1y : c2_0y);
    float s2x = a0 ? (a1 ? c2_3x : c2_2x) : (a1 ? c2_1x : c2_0x);
    float s2d = a0 ? (a1 ? d2_3 : d2_2) : (a1 ? d2_1 : d2_0);
    bool a2 = s2d < curd;
    y = a2 ? s2y : y;  x = a2 ? s2x : x;  curd = a2 ? s2d : curd;

    float s3y = a0 ? (a1 ? (a2 ? c3_7y : c3_6y) : (a2 ? c3_5y : c3_4y))
                   : (a1 ? (a2 ? c3_3y : c3_2y) : (a2 ? c3_1y : c3_0y));
    float s3x = a0 ? (a1 ? (a2 ? c3_7x : c3_6x) : (a2 ? c3_5x : c3_4x))
                   : (a1 ? (a2 ? c3_3x : c3_2x) : (a2 ? c3_1x : c3_0x));
    float s3d = a0 ? (a1 ? (a2 ? d3_7 : d3_6) : (a2 ? d3_5 : d3_4))
                   : (a1 ? (a2 ? d3_3 : d3_2) : (a2 ? d3_1 : d3_0));
    bool a3 = s3d < curd;
    y = a3 ? s3y : y;  x = a3 ? s3x : x;  curd = a3 ? s3d : curd;
  }
  out[idx_y] = y;
  out[idx_x] = x;
}

__global__ __launch_bounds__(256) void compute_d(const float* __restrict__ S,
                                                 const float* __restrict__ T,
                                                 float* __restrict__ D) {
  const int x = threadIdx.x;
  const int y = blockIdx.x & 255;
  const int b = blockIdx.x >> 8;
  const int chs = 65536;
  const float* Sb = S + (size_t)b * 32 * chs;
  const float* Tb = T + (size_t)b * 32 * chs;
  float acc = 0.0f;
  for (int py = 0; py < 3; ++py) {
    int yy = y + py - 1;
    if (yy < 0 || yy > 255) continue;
    for (int px = 0; px < 3; ++px) {
      int xx = x + px - 1;
      if (xx < 0 || xx > 255) continue;
      int off = yy * 256 + xx;
      for (int c = 0; c < 32; ++c) {
        float d = subf(Sb[c * chs + off], Tb[c * chs + off]);
        acc = addf(acc, mulf(d, d));
      }
    }
  }
  D[b * chs + y * 256 + x] = acc;
}

__global__ __launch_bounds__(256) void pm_kernel(const float* __restrict__ D,
                                                 float* __restrict__ out,
                                                 PMKeys K) {
  const int j = threadIdx.x;
  const int bb = blockIdx.x >> 8;
  const int i = blockIdx.x & 255;
  const float* Db = D + bb * 65536;
  __shared__ float sy[256], sx[256];

  const uint32_t idx_y = (uint32_t)(bb * 131072 + i * 256 + j);
  const uint32_t idx_x = idx_y + 65536u;

  float y = mulf(unitf(tf_bits32(K.ki0, K.ki1, idx_y)), 255.0f);
  float x = mulf(unitf(tf_bits32(K.ki0, K.ki1, idx_x)), 255.0f);

  auto lookup = [&](float yy, float xx) -> float {
    int iy = (int)rintf(yy);
    int ix = (int)rintf(xx);
    iy = min(max(iy, 0), 255);
    ix = min(max(ix, 0), 255);
    return Db[iy * 256 + ix];
  };

  for (int t = 0; t < 5; ++t) {
    sy[j] = y; sx[j] = x;
    __syncthreads();
    {
      int jn = (j + 255) & 255;
      float yn = sy[jn], xn = sx[jn];
      float cur = lookup(y, x);
      float shf = lookup(yn, xn);
      if (shf < cur) { y = yn; x = xn; }
    }
    __syncthreads();
    sy[j] = y; sx[j] = x;
    __syncthreads();
    {
      int jn = (j + 1) & 255;
      float yn = sy[jn], xn = sx[jn];
      float cur = lookup(y, x);
      float shf = lookup(yn, xn);
      if (shf < cur) { y = yn; x = xn; }
    }
    __syncthreads();
    float cur = lookup(y, x);
    float sigma = 1.0f;
    for (int s = 0; s < 4; ++s) {
      uint32_t kk0 = K.sk[t][s][0], kk1 = K.sk[t][s][1];
      float ny = jax_normal(tf_bits32(kk0, kk1, idx_y));
      float nx = jax_normal(tf_bits32(kk0, kk1, idx_x));
      float ry = fminf(fmaxf(addf(y, mulf(ny, sigma)), 0.0f), 255.0f);
      float rx = fminf(fmaxf(addf(x, mulf(nx, sigma)), 0.0f), 255.0f);
      float rd = lookup(ry, rx);
      if (rd < cur) { y = ry; x = rx; cur = rd; }
      sigma *= 0.5f;
    }
  }
  out[idx_y] = y;
  out[idx_x] = x;
}

// ---------- host-side threefry ----------
static void h_tf(uint32_t k0, uint32_t k1, uint32_t x0, uint32_t x1,
                 uint32_t& o0, uint32_t& o1) {
  uint32_t ks2 = k0 ^ k1 ^ 0x1BD11BDAu;
  x0 += k0; x1 += k1;
#define HR(d) { x0 += x1; x1 = (x1 << (d)) | (x1 >> (32 - (d))); x1 ^= x0; }
  HR(13) HR(15) HR(26) HR(6)
  x0 += k1; x1 += ks2 + 1u;
  HR(17) HR(29) HR(16) HR(24)
  x0 += ks2; x1 += k0 + 2u;
  HR(13) HR(15) HR(26) HR(6)
  x0 += k0; x1 += k1 + 3u;
  HR(17) HR(29) HR(16) HR(24)
  x0 += k1; x1 += ks2 + 4u;
  HR(13) HR(15) HR(26) HR(6)
  x0 += ks2; x1 += k0 + 5u;
#undef HR
  o0 = x0; o1 = x1;
}

extern "C" void kernel_launch(void* const* d_in, const int* in_sizes, int n_in,
                              void* d_out, int out_size, void* d_ws, size_t ws_size,
                              hipStream_t stream) {
  const float* S = (const float*)d_in[0];
  const float* T = (const float*)d_in[1];
  float* out = (float*)d_out;

  PMKeys K;
  uint32_t kl0, kl1;
  h_tf(0u, 1u, 0u, 0u, K.ki0, K.ki1);
  h_tf(0u, 1u, 0u, 1u, kl0, kl1);
  for (uint32_t t = 0; t < 5; ++t) {
    uint32_t c0, c1;
    h_tf(kl0, kl1, 0u, t, c0, c1);
    for (int s = 0; s < 4; ++s) {
      uint32_t n0, n1, s0, s1;
      h_tf(c0, c1, 0u, 0u, n0, n1);
      h_tf(c0, c1, 0u, 1u, s0, s1);
      K.sk[t][s][0] = s0; K.sk[t][s][1] = s1;
      c0 = n0; c1 = n1;
    }
  }

  const size_t D_BYTES = 2ull * 65536 * 4;       // 512 KB
  const size_t Q_BYTES = 2ull * 65536 * 32 * 4;  // 16.8 MB (cq-planar)
  const size_t N_BYTES = 20ull * 262144 * 4;     // 20 MB
  const size_t NEED = D_BYTES + Q_BYTES + N_BYTES;

  if (ws_size >= NEED) {
    float* Dd = (float*)d_ws;
    float4* Qq = (float4*)((char*)d_ws + D_BYTES);
    float* Nn = (float*)((char*)d_ws + D_BYTES + Q_BYTES);
    NK nk;
    for (int t = 0; t < 5; ++t)
      for (int s = 0; s < 4; ++s) {
        nk.k[t * 4 + s][0] = K.sk[t][s][0];
        nk.k[t * 4 + s][1] = K.sk[t][s][1];
      }

    // cooperative capacity check (non-stream API calls; capture-safe)
    int coop = 0, dev = 0, maxb = 0;
    hipGetDevice(&dev);
    hipDeviceGetAttribute(&coop, hipDeviceAttributeCooperativeLaunch, dev);
    hipOccupancyMaxActiveBlocksPerMultiprocessor(&maxb, (const void*)mega, 256, 0);

    if (coop && maxb >= 4) {
      const float4* S4 = (const float4*)S;
      const float4* T4 = (const float4*)T;
      uint32_t ki0 = K.ki0, ki1 = K.ki1;
      void* args[] = {(void*)&S4, (void*)&T4, (void*)&Qq, (void*)&Nn,
                      (void*)&Dd, (void*)&out, (void*)&nk, (void*)&ki0, (void*)&ki1};
      hipLaunchCooperativeKernel((const void*)mega, dim3(1024), dim3(256),
                                 args, 0, stream);
    } else {
      hipLaunchKernelGGL(qdiff_n, dim3(2048), dim3(256), 0, stream,
                         (const float4*)S, (const float4*)T, Qq, Nn, nk);
      hipLaunchKernelGGL(dsum3, dim3(512), dim3(256), 0, stream, Qq, Dd);
      hipLaunchKernelGGL(pm_fast, dim3(512), dim3(256), 0, stream, Dd, Nn, out, K.ki0, K.ki1);
    }
  } else {
    float* Dd = (float*)d_ws;
    hipLaunchKernelGGL(compute_d, dim3(512), dim3(256), 0, stream, S, T, Dd);
    hipLaunchKernelGGL(pm_kernel, dim3(512), dim3(256), 0, stream, Dd, out, K);
  }
}

// Round 12
// 116.392 us; speedup vs baseline: 1.0153x; 1.0147x over previous
//
#include <hip/hip_runtime.h>
#include <stdint.h>

#define DEVFN __device__ __forceinline__

// ---------- strict f32 ops (no FMA contraction, matches XLA strict mode) ----------
DEVFN float mulf(float a, float b) {
#pragma clang fp contract(off)
  return a * b;
}
DEVFN float addf(float a, float b) {
#pragma clang fp contract(off)
  return a + b;
}
DEVFN float subf(float a, float b) {
#pragma clang fp contract(off)
  return a - b;
}

// ---------- threefry2x32 (JAX), partitionable counter scheme ----------
DEVFN uint32_t tf_bits32(uint32_t k0, uint32_t k1, uint32_t ctr) {
  uint32_t ks2 = k0 ^ k1 ^ 0x1BD11BDAu;
  uint32_t x0 = k0;
  uint32_t x1 = ctr + k1;
#define TFR(d) { x0 += x1; x1 = (x1 << (d)) | (x1 >> (32 - (d))); x1 ^= x0; }
  TFR(13) TFR(15) TFR(26) TFR(6)
  x0 += k1; x1 += ks2 + 1u;
  TFR(17) TFR(29) TFR(16) TFR(24)
  x0 += ks2; x1 += k0 + 2u;
  TFR(13) TFR(15) TFR(26) TFR(6)
  x0 += k0; x1 += k1 + 3u;
  TFR(17) TFR(29) TFR(16) TFR(24)
  x0 += k1; x1 += ks2 + 4u;
  TFR(13) TFR(15) TFR(26) TFR(6)
  x0 += ks2; x1 += k0 + 5u;
#undef TFR
  return x0 ^ x1;
}

// ---------- XLA-CPU Cephes log, unfused ----------
DEVFN float xla_cephes_logf(float in) {
  float xv = fmaxf(in, __uint_as_float(0x00800000u));
  uint32_t bits = __float_as_uint(xv);
  int ei = (int)(bits >> 23) - 126;
  float m = __uint_as_float((bits & 0x007FFFFFu) | 0x3F000000u);
  float e = (float)ei;
  const float SQRTHF = __uint_as_float(0x3F3504F3u);
  bool lt = m < SQRTHF;
  float tmp = lt ? m : 0.0f;
  m = subf(m, 1.0f);
  e = subf(e, lt ? 1.0f : 0.0f);
  m = addf(m, tmp);
  float z = mulf(m, m);
  float y = 7.0376836292E-2f;
  y = addf(mulf(y, m), -1.1514610310E-1f);
  y = addf(mulf(y, m),  1.1676998740E-1f);
  y = addf(mulf(y, m), -1.2420140846E-1f);
  y = addf(mulf(y, m),  1.4249322787E-1f);
  y = addf(mulf(y, m), -1.6668057665E-1f);
  y = addf(mulf(y, m),  2.0000714765E-1f);
  y = addf(mulf(y, m), -2.4999993993E-1f);
  y = addf(mulf(y, m),  3.3333331174E-1f);
  y = mulf(y, m);
  y = mulf(y, z);
  y = addf(y, mulf(e, -2.12194440e-4f));
  y = subf(y, mulf(z, 0.5f));
  m = addf(m, y);
  m = addf(m, mulf(e, 0.693359375f));
  return m;
}

DEVFN float xla_log1pf(float a) {
  float large = xla_cephes_logf(addf(a, 1.0f));
  float small = mulf(addf(mulf(-0.5f, a), 1.0f), a);
  return (fabsf(a) < __uint_as_float(0x38D1B717u)) ? small : large;
}

DEVFN float xla_erfinvf(float u) {
  float nxx = -mulf(u, u);
  float w = -xla_log1pf(nxx);
  float p;
  if (w < 5.0f) {
    float s = subf(w, 2.5f);
    p = 2.81022636e-08f;
    p = addf(mulf(p, s), 3.43273939e-07f);
    p = addf(mulf(p, s), -3.5233877e-06f);
    p = addf(mulf(p, s), -4.39150654e-06f);
    p = addf(mulf(p, s), 0.00021858087f);
    p = addf(mulf(p, s), -0.00125372503f);
    p = addf(mulf(p, s), -0.00417768164f);
    p = addf(mulf(p, s), 0.246640727f);
    p = addf(mulf(p, s), 1.50140941f);
  } else {
    float s = subf(__fsqrt_rn(w), 3.0f);
    p = -0.000200214257f;
    p = addf(mulf(p, s), 0.000100950558f);
    p = addf(mulf(p, s), 0.00134934322f);
    p = addf(mulf(p, s), -0.00367342844f);
    p = addf(mulf(p, s), 0.00573950773f);
    p = addf(mulf(p, s), -0.0076224613f);
    p = addf(mulf(p, s), 0.00943887047f);
    p = addf(mulf(p, s), 1.00167406f);
    p = addf(mulf(p, s), 2.83297682f);
  }
  return mulf(p, u);
}

DEVFN float unitf(uint32_t bits) {
  return subf(__uint_as_float((bits >> 9) | 0x3F800000u), 1.0f);
}

DEVFN float jax_normal(uint32_t bits) {
  float f = unitf(bits);
  const float lo = __uint_as_float(0xBF7FFFFFu);
  float u = fmaxf(lo, addf(mulf(f, 2.0f), lo));
  const float sqrt2 = __uint_as_float(0x3FB504F3u);
  return mulf(sqrt2, xla_erfinvf(u));
}

struct PMKeys {
  uint32_t ki0, ki1;
  uint32_t sk[5][4][2];
};
struct NK { uint32_t k[20][2]; };

DEVFN float candf(float base, float n, float sig) {
  return fminf(fmaxf(addf(base, mulf(n, sig)), 0.0f), 255.0f);
}
DEVFN int addr_of(float yy, float xx) {
  int iy = (int)rintf(yy);
  int ix = (int)rintf(xx);
  iy = min(max(iy, 0), 255);
  ix = min(max(ix, 0), 255);
  return iy * 256 + ix;
}

// ========================================================================
// FAST PATH (R9 configuration — best measured: 117.3 µs)
// ========================================================================

// K1: Q4[b][y][cq][x] (float4 = channels 4cq..4cq+3) = (S-T)^2 via LDS
// transpose; float4-vectorized S/T loads; inline 10 jax normals per thread
// slotted while the loads are in flight. 2048 blocks, 8.7 KB LDS.
__global__ __launch_bounds__(256) void qdiff_n(const float4* __restrict__ S4,
                                               const float4* __restrict__ T4,
                                               float4* __restrict__ Q4,
                                               float* __restrict__ N,
                                               NK nk) {
  __shared__ float lds[64 * 33];
  const int t = threadIdx.x;
  const int bid = blockIdx.x;
  const int xcd = bid & 7;
  const int slot = bid >> 3;
  const int r = xcd * 64 + (slot >> 2);  // 0..511 == b*256 + y
  const int q = slot & 3;
  const int b = r >> 8;
  const int y = r & 255;
  const int x0 = q << 6;
  const int c = t >> 3;
  const int j0 = t & 7;

  const size_t fbase = (size_t)(b * 32 + c) * 16384 + (size_t)y * 64 + (x0 >> 2);
  float4 s0 = S4[fbase + j0];
  float4 s1 = S4[fbase + j0 + 8];
  float4 t0 = T4[fbase + j0];
  float4 t1 = T4[fbase + j0 + 8];

  uint32_t gtid = (uint32_t)bid * 256u + (uint32_t)t;
#pragma unroll
  for (int i = 0; i < 10; ++i) {
    uint32_t L = (uint32_t)i * 524288u + gtid;
    uint32_t ts = L >> 18;
    uint32_t idx = L & 262143u;
    N[L] = jax_normal(tf_bits32(nk.k[ts][0], nk.k[ts][1], idx));
  }

  {
    float d;
    int p0 = (j0 << 2) * 33 + c;
    d = subf(s0.x, t0.x); lds[p0]      = mulf(d, d);
    d = subf(s0.y, t0.y); lds[p0 + 33] = mulf(d, d);
    d = subf(s0.z, t0.z); lds[p0 + 66] = mulf(d, d);
    d = subf(s0.w, t0.w); lds[p0 + 99] = mulf(d, d);
    int p1 = ((j0 + 8) << 2) * 33 + c;
    d = subf(s1.x, t1.x); lds[p1]      = mulf(d, d);
    d = subf(s1.y, t1.y); lds[p1 + 33] = mulf(d, d);
    d = subf(s1.z, t1.z); lds[p1 + 66] = mulf(d, d);
    d = subf(s1.w, t1.w); lds[p1 + 99] = mulf(d, d);
  }
  __syncthreads();
  const size_t base4 = (((size_t)b * 256 + y) * 8) * 256;
#pragma unroll
  for (int k = 0; k < 2; ++k) {
    int cq = (k << 2) + (t >> 6);
    int px = t & 63;
    int lb = px * 33 + cq * 4;
    float4 v;
    v.x = lds[lb]; v.y = lds[lb + 1]; v.z = lds[lb + 2]; v.w = lds[lb + 3];
    Q4[base4 + (size_t)cq * 256 + x0 + px] = v;
  }
}

// K2: D[b][y][x] strict (py,px,c) linear chain from cq-planar Q4.
// unroll-1 keeps one tap's 8 float4 live at a time (bounded VGPR).
__global__ __launch_bounds__(256) void dsum3(const float4* __restrict__ Q4,
                                             float* __restrict__ D) {
  const int x = threadIdx.x;
  const int bid = blockIdx.x;
  const int swz = (bid & 7) * 64 + (bid >> 3);
  const int y = swz & 255;
  const int b = swz >> 8;
  const float4* Qb = Q4 + (size_t)b * 524288;

  float acc = 0.0f;
#pragma unroll 1
  for (int py = 0; py < 3; ++py) {
    int yy = y + py - 1;
    if (yy < 0 || yy > 255) continue;
    const float4* Qrow = Qb + (size_t)yy * 2048;
#pragma unroll 1
    for (int px = 0; px < 3; ++px) {
      int xx = x + px - 1;
      if (xx < 0 || xx > 255) continue;
      float4 v0 = Qrow[xx];
      float4 v1 = Qrow[256 + xx];
      float4 v2 = Qrow[512 + xx];
      float4 v3 = Qrow[768 + xx];
      float4 v4 = Qrow[1024 + xx];
      float4 v5 = Qrow[1280 + xx];
      float4 v6 = Qrow[1536 + xx];
      float4 v7 = Qrow[1792 + xx];
      acc = addf(acc, v0.x); acc = addf(acc, v0.y); acc = addf(acc, v0.z); acc = addf(acc, v0.w);
      acc = addf(acc, v1.x); acc = addf(acc, v1.y); acc = addf(acc, v1.z); acc = addf(acc, v1.w);
      acc = addf(acc, v2.x); acc = addf(acc, v2.y); acc = addf(acc, v2.z); acc = addf(acc, v2.w);
      acc = addf(acc, v3.x); acc = addf(acc, v3.y); acc = addf(acc, v3.z); acc = addf(acc, v3.w);
      acc = addf(acc, v4.x); acc = addf(acc, v4.y); acc = addf(acc, v4.z); acc = addf(acc, v4.w);
      acc = addf(acc, v5.x); acc = addf(acc, v5.y); acc = addf(acc, v5.z); acc = addf(acc, v5.w);
      acc = addf(acc, v6.x); acc = addf(acc, v6.y); acc = addf(acc, v6.z); acc = addf(acc, v6.w);
      acc = addf(acc, v7.x); acc = addf(acc, v7.y); acc = addf(acc, v7.z); acc = addf(acc, v7.w);
    }
  }
  D[(b * 256 + y) * 256 + x] = acc;
}

// K3: PatchMatch loop with speculative-acceptance-tree random search
// (15 concurrent loads, nested-select resolution — bitwise identical).
__global__ __launch_bounds__(256) void pm_fast(const float* __restrict__ D,
                                               const float* __restrict__ N,
                                               float* __restrict__ out,
                                               uint32_t ki0, uint32_t ki1) {
  const int j = threadIdx.x;
  const int bb = blockIdx.x >> 8;
  const int i = blockIdx.x & 255;
  const float* Db = D + bb * 65536;
  __shared__ float sy[256], sx[256];

  const uint32_t idx_y = (uint32_t)(bb * 131072 + i * 256 + j);
  const uint32_t idx_x = idx_y + 65536u;

  float nyv[20], nxv[20];
#pragma unroll
  for (int ts = 0; ts < 20; ++ts) {
    nyv[ts] = N[(size_t)ts * 262144 + idx_y];
    nxv[ts] = N[(size_t)ts * 262144 + idx_x];
  }

  float y = mulf(unitf(tf_bits32(ki0, ki1, idx_y)), 255.0f);
  float x = mulf(unitf(tf_bits32(ki0, ki1, idx_x)), 255.0f);

  float curd = Db[addr_of(y, x)];
#pragma unroll
  for (int t = 0; t < 5; ++t) {
    sy[j] = y; sx[j] = x;
    __syncthreads();
    {
      int jn = (j + 255) & 255;
      float yn = sy[jn], xn = sx[jn];
      float shf = Db[addr_of(yn, xn)];
      if (shf < curd) { y = yn; x = xn; curd = shf; }
    }
    __syncthreads();
    sy[j] = y; sx[j] = x;
    __syncthreads();
    {
      int jn = (j + 1) & 255;
      float yn = sy[jn], xn = sx[jn];
      float shf = Db[addr_of(yn, xn)];
      if (shf < curd) { y = yn; x = xn; curd = shf; }
    }
    __syncthreads();

    float n0y = nyv[t * 4 + 0], n0x = nxv[t * 4 + 0];
    float n1y = nyv[t * 4 + 1], n1x = nxv[t * 4 + 1];
    float n2y = nyv[t * 4 + 2], n2x = nxv[t * 4 + 2];
    float n3y = nyv[t * 4 + 3], n3x = nxv[t * 4 + 3];

    float c0y = candf(y, n0y, 1.0f),  c0x = candf(x, n0x, 1.0f);
    float c1Ay = candf(y,   n1y, 0.5f), c1Ax = candf(x,   n1x, 0.5f);
    float c1By = candf(c0y, n1y, 0.5f), c1Bx = candf(c0x, n1x, 0.5f);
    float c2_0y = candf(y,    n2y, 0.25f), c2_0x = candf(x,    n2x, 0.25f);
    float c2_1y = candf(c1Ay, n2y, 0.25f), c2_1x = candf(c1Ax, n2x, 0.25f);
    float c2_2y = candf(c0y,  n2y, 0.25f), c2_2x = candf(c0x,  n2x, 0.25f);
    float c2_3y = candf(c1By, n2y, 0.25f), c2_3x = candf(c1Bx, n2x, 0.25f);
    float c3_0y = candf(y,     n3y, 0.125f), c3_0x = candf(x,     n3x, 0.125f);
    float c3_1y = candf(c2_0y, n3y, 0.125f), c3_1x = candf(c2_0x, n3x, 0.125f);
    float c3_2y = candf(c1Ay,  n3y, 0.125f), c3_2x = candf(c1Ax,  n3x, 0.125f);
    float c3_3y = candf(c2_1y, n3y, 0.125f), c3_3x = candf(c2_1x, n3x, 0.125f);
    float c3_4y = candf(c0y,   n3y, 0.125f), c3_4x = candf(c0x,   n3x, 0.125f);
    float c3_5y = candf(c2_2y, n3y, 0.125f), c3_5x = candf(c2_2x, n3x, 0.125f);
    float c3_6y = candf(c1By,  n3y, 0.125f), c3_6x = candf(c1Bx,  n3x, 0.125f);
    float c3_7y = candf(c2_3y, n3y, 0.125f), c3_7x = candf(c2_3x, n3x, 0.125f);

    float d0   = Db[addr_of(c0y,  c0x)];
    float d1A  = Db[addr_of(c1Ay, c1Ax)];
    float d1B  = Db[addr_of(c1By, c1Bx)];
    float d2_0 = Db[addr_of(c2_0y, c2_0x)];
    float d2_1 = Db[addr_of(c2_1y, c2_1x)];
    float d2_2 = Db[addr_of(c2_2y, c2_2x)];
    float d2_3 = Db[addr_of(c2_3y, c2_3x)];
    float d3_0 = Db[addr_of(c3_0y, c3_0x)];
    float d3_1 = Db[addr_of(c3_1y, c3_1x)];
    float d3_2 = Db[addr_of(c3_2y, c3_2x)];
    float d3_3 = Db[addr_of(c3_3y, c3_3x)];
    float d3_4 = Db[addr_of(c3_4y, c3_4x)];
    float d3_5 = Db[addr_of(c3_5y, c3_5x)];
    float d3_6 = Db[addr_of(c3_6y, c3_6x)];
    float d3_7 = Db[addr_of(c3_7y, c3_7x)];

    bool a0 = d0 < curd;
    y = a0 ? c0y : y;  x = a0 ? c0x : x;  curd = a0 ? d0 : curd;

    float s1y = a0 ? c1By : c1Ay, s1x = a0 ? c1Bx : c1Ax, s1d = a0 ? d1B : d1A;
    bool a1 = s1d < curd;
    y = a1 ? s1y : y;  x = a1 ? s1x : x;  curd = a1 ? s1d : curd;

    float s2y = a0 ? (a1 ? c2_3y : c2_2y) : (a1 ? c2_1y : c2_0y);
    float s2x = a0 ? (a1 ? c2_3x : c2_2x) : (a1 ? c2_1x : c2_0x);
    float s2d = a0 ? (a1 ? d2_3 : d2_2) : (a1 ? d2_1 : d2_0);
    bool a2 = s2d < curd;
    y = a2 ? s2y : y;  x = a2 ? s2x : x;  curd = a2 ? s2d : curd;

    float s3y = a0 ? (a1 ? (a2 ? c3_7y : c3_6y) : (a2 ? c3_5y : c3_4y))
                   : (a1 ? (a2 ? c3_3y : c3_2y) : (a2 ? c3_1y : c3_0y));
    float s3x = a0 ? (a1 ? (a2 ? c3_7x : c3_6x) : (a2 ? c3_5x : c3_4x))
                   : (a1 ? (a2 ? c3_3x : c3_2x) : (a2 ? c3_1x : c3_0x));
    float s3d = a0 ? (a1 ? (a2 ? d3_7 : d3_6) : (a2 ? d3_5 : d3_4))
                   : (a1 ? (a2 ? d3_3 : d3_2) : (a2 ? d3_1 : d3_0));
    bool a3 = s3d < curd;
    y = a3 ? s3y : y;  x = a3 ? s3x : x;  curd = a3 ? s3d : curd;
  }
  out[idx_y] = y;
  out[idx_x] = x;
}

// ========================================================================
// FALLBACK PATH (round-1, proven) — used if ws_size too small
// ========================================================================

__global__ __launch_bounds__(256) void compute_d(const float* __restrict__ S,
                                                 const float* __restrict__ T,
                                                 float* __restrict__ D) {
  const int x = threadIdx.x;
  const int y = blockIdx.x & 255;
  const int b = blockIdx.x >> 8;
  const int chs = 65536;
  const float* Sb = S + (size_t)b * 32 * chs;
  const float* Tb = T + (size_t)b * 32 * chs;
  float acc = 0.0f;
  for (int py = 0; py < 3; ++py) {
    int yy = y + py - 1;
    if (yy < 0 || yy > 255) continue;
    for (int px = 0; px < 3; ++px) {
      int xx = x + px - 1;
      if (xx < 0 || xx > 255) continue;
      int off = yy * 256 + xx;
      for (int c = 0; c < 32; ++c) {
        float d = subf(Sb[c * chs + off], Tb[c * chs + off]);
        acc = addf(acc, mulf(d, d));
      }
    }
  }
  D[b * chs + y * 256 + x] = acc;
}

__global__ __launch_bounds__(256) void pm_kernel(const float* __restrict__ D,
                                                 float* __restrict__ out,
                                                 PMKeys K) {
  const int j = threadIdx.x;
  const int bb = blockIdx.x >> 8;
  const int i = blockIdx.x & 255;
  const float* Db = D + bb * 65536;
  __shared__ float sy[256], sx[256];

  const uint32_t idx_y = (uint32_t)(bb * 131072 + i * 256 + j);
  const uint32_t idx_x = idx_y + 65536u;

  float y = mulf(unitf(tf_bits32(K.ki0, K.ki1, idx_y)), 255.0f);
  float x = mulf(unitf(tf_bits32(K.ki0, K.ki1, idx_x)), 255.0f);

  auto lookup = [&](float yy, float xx) -> float {
    int iy = (int)rintf(yy);
    int ix = (int)rintf(xx);
    iy = min(max(iy, 0), 255);
    ix = min(max(ix, 0), 255);
    return Db[iy * 256 + ix];
  };

  for (int t = 0; t < 5; ++t) {
    sy[j] = y; sx[j] = x;
    __syncthreads();
    {
      int jn = (j + 255) & 255;
      float yn = sy[jn], xn = sx[jn];
      float cur = lookup(y, x);
      float shf = lookup(yn, xn);
      if (shf < cur) { y = yn; x = xn; }
    }
    __syncthreads();
    sy[j] = y; sx[j] = x;
    __syncthreads();
    {
      int jn = (j + 1) & 255;
      float yn = sy[jn], xn = sx[jn];
      float cur = lookup(y, x);
      float shf = lookup(yn, xn);
      if (shf < cur) { y = yn; x = xn; }
    }
    __syncthreads();
    float cur = lookup(y, x);
    float sigma = 1.0f;
    for (int s = 0; s < 4; ++s) {
      uint32_t kk0 = K.sk[t][s][0], kk1 = K.sk[t][s][1];
      float ny = jax_normal(tf_bits32(kk0, kk1, idx_y));
      float nx = jax_normal(tf_bits32(kk0, kk1, idx_x));
      float ry = fminf(fmaxf(addf(y, mulf(ny, sigma)), 0.0f), 255.0f);
      float rx = fminf(fmaxf(addf(x, mulf(nx, sigma)), 0.0f), 255.0f);
      float rd = lookup(ry, rx);
      if (rd < cur) { y = ry; x = rx; cur = rd; }
      sigma *= 0.5f;
    }
  }
  out[idx_y] = y;
  out[idx_x] = x;
}

// ---------- host-side threefry ----------
static void h_tf(uint32_t k0, uint32_t k1, uint32_t x0, uint32_t x1,
                 uint32_t& o0, uint32_t& o1) {
  uint32_t ks2 = k0 ^ k1 ^ 0x1BD11BDAu;
  x0 += k0; x1 += k1;
#define HR(d) { x0 += x1; x1 = (x1 << (d)) | (x1 >> (32 - (d))); x1 ^= x0; }
  HR(13) HR(15) HR(26) HR(6)
  x0 += k1; x1 += ks2 + 1u;
  HR(17) HR(29) HR(16) HR(24)
  x0 += ks2; x1 += k0 + 2u;
  HR(13) HR(15) HR(26) HR(6)
  x0 += k0; x1 += k1 + 3u;
  HR(17) HR(29) HR(16) HR(24)
  x0 += k1; x1 += ks2 + 4u;
  HR(13) HR(15) HR(26) HR(6)
  x0 += ks2; x1 += k0 + 5u;
#undef HR
  o0 = x0; o1 = x1;
}

extern "C" void kernel_launch(void* const* d_in, const int* in_sizes, int n_in,
                              void* d_out, int out_size, void* d_ws, size_t ws_size,
                              hipStream_t stream) {
  const float* S = (const float*)d_in[0];
  const float* T = (const float*)d_in[1];
  float* out = (float*)d_out;

  PMKeys K;
  uint32_t kl0, kl1;
  h_tf(0u, 1u, 0u, 0u, K.ki0, K.ki1);
  h_tf(0u, 1u, 0u, 1u, kl0, kl1);
  for (uint32_t t = 0; t < 5; ++t) {
    uint32_t c0, c1;
    h_tf(kl0, kl1, 0u, t, c0, c1);
    for (int s = 0; s < 4; ++s) {
      uint32_t n0, n1, s0, s1;
      h_tf(c0, c1, 0u, 0u, n0, n1);
      h_tf(c0, c1, 0u, 1u, s0, s1);
      K.sk[t][s][0] = s0; K.sk[t][s][1] = s1;
      c0 = n0; c1 = n1;
    }
  }

  const size_t D_BYTES = 2ull * 65536 * 4;       // 512 KB
  const size_t Q_BYTES = 2ull * 65536 * 32 * 4;  // 16.8 MB (cq-planar)
  const size_t N_BYTES = 20ull * 262144 * 4;     // 20 MB
  const size_t NEED = D_BYTES + Q_BYTES + N_BYTES;

  if (ws_size >= NEED) {
    float* Dd = (float*)d_ws;
    float4* Qq = (float4*)((char*)d_ws + D_BYTES);
    float* Nn = (float*)((char*)d_ws + D_BYTES + Q_BYTES);
    NK nk;
    for (int t = 0; t < 5; ++t)
      for (int s = 0; s < 4; ++s) {
        nk.k[t * 4 + s][0] = K.sk[t][s][0];
        nk.k[t * 4 + s][1] = K.sk[t][s][1];
      }
    hipLaunchKernelGGL(qdiff_n, dim3(2048), dim3(256), 0, stream,
                       (const float4*)S, (const float4*)T, Qq, Nn, nk);
    hipLaunchKernelGGL(dsum3, dim3(512), dim3(256), 0, stream, Qq, Dd);
    hipLaunchKernelGGL(pm_fast, dim3(512), dim3(256), 0, stream, Dd, Nn, out, K.ki0, K.ki1);
  } else {
    float* Dd = (float*)d_ws;
    hipLaunchKernelGGL(compute_d, dim3(512), dim3(256), 0, stream, S, T, Dd);
    hipLaunchKernelGGL(pm_kernel, dim3(512), dim3(256), 0, stream, Dd, out, K);
  }
}